// Round 3
// baseline (34059.756 us; speedup 1.0000x reference)
//
#include <hip/hip_runtime.h>
#include <cstddef>
#include <cstdint>

// CustomLSTM: T=512, B=64, I=H=1024, L=2. fp32 in/out, bf16 MFMA internally.
#define T_LEN   512
#define BATCH   64
#define IN_DIM  1024
#define HID     1024
#define GATES   4096
#define NLAYERS 2
#define TCHUNK  64
#define NBLK    64      // persistent blocks (1/CU on 64 CUs)
#define NTHR    512     // 8 waves

typedef __bf16 bf16;
typedef __bf16 bf16x8 __attribute__((ext_vector_type(8)));
typedef float  f32x4  __attribute__((ext_vector_type(4)));

// ---------------------------------------------------------------------------
__global__ __launch_bounds__(256) void cvt_bf16(const float* __restrict__ in,
                                                bf16* __restrict__ out, int n4) {
    int i = blockIdx.x * blockDim.x + threadIdx.x;
    if (i >= n4) return;
    float4 v = ((const float4*)in)[i];
    bf16 o[4] = {(bf16)v.x, (bf16)v.y, (bf16)v.z, (bf16)v.w};
    *(uint2*)(out + 4 * (size_t)i) = *(uint2*)o;
}

// ---------------------------------------------------------------------------
// Input projection GEMM (NT, bf16 MFMA): C[m][n] = A[m][:]·W[n][:] + bias[n]
// (unchanged from round 2 — verified working, ~0.1 ms per 4096^2x1024 call)
// ---------------------------------------------------------------------------
template <bool AF32>
__global__ __launch_bounds__(256) void gemm_xin(
    const void* __restrict__ Aptr, const bf16* __restrict__ W,
    const float* __restrict__ bih, const float* __restrict__ bhh,
    float* __restrict__ C)
{
    __shared__ bf16 As[128 * 40];
    __shared__ bf16 Bs[128 * 40];

    const int m0 = blockIdx.y * 128;
    const int n0 = blockIdx.x * 128;
    const int tid  = threadIdx.x;
    const int lane = tid & 63;
    const int wv   = tid >> 6;
    const int wm   = (wv & 1) * 64;
    const int wn   = (wv >> 1) * 64;
    const int quad = lane >> 4;
    const int l16  = lane & 15;

    f32x4 acc[4][4] = {};

    for (int k0 = 0; k0 < IN_DIM; k0 += 32) {
        if constexpr (AF32) {
            const float* A = (const float*)Aptr;
            const int row = tid >> 3;
            const int ko  = (tid & 7) * 4;
            #pragma unroll
            for (int p = 0; p < 4; ++p) {
                int r = row + 32 * p;
                float4 v = *(const float4*)(A + (size_t)(m0 + r) * IN_DIM + k0 + ko);
                bf16 o[4] = {(bf16)v.x, (bf16)v.y, (bf16)v.z, (bf16)v.w};
                *(uint2*)&As[r * 40 + ko] = *(uint2*)o;
            }
        } else {
            const bf16* A = (const bf16*)Aptr;
            const int row = tid >> 2;
            const int ko  = (tid & 3) * 8;
            *(uint4*)&As[row * 40 + ko] =
                *(const uint4*)(A + (size_t)(m0 + row) * IN_DIM + k0 + ko);
            *(uint4*)&As[(row + 64) * 40 + ko] =
                *(const uint4*)(A + (size_t)(m0 + row + 64) * IN_DIM + k0 + ko);
        }
        {
            const int row = tid >> 2;
            const int ko  = (tid & 3) * 8;
            *(uint4*)&Bs[row * 40 + ko] =
                *(const uint4*)(W + (size_t)(n0 + row) * IN_DIM + k0 + ko);
            *(uint4*)&Bs[(row + 64) * 40 + ko] =
                *(const uint4*)(W + (size_t)(n0 + row + 64) * IN_DIM + k0 + ko);
        }
        __syncthreads();

        bf16x8 af[4], bfr[4];
        #pragma unroll
        for (int t = 0; t < 4; ++t) {
            af[t]  = *(const bf16x8*)&As[(wm + t * 16 + l16) * 40 + quad * 8];
            bfr[t] = *(const bf16x8*)&Bs[(wn + t * 16 + l16) * 40 + quad * 8];
        }
        #pragma unroll
        for (int mt = 0; mt < 4; ++mt)
            #pragma unroll
            for (int nt = 0; nt < 4; ++nt)
                acc[mt][nt] = __builtin_amdgcn_mfma_f32_16x16x32_bf16(
                    af[mt], bfr[nt], acc[mt][nt], 0, 0, 0);
        __syncthreads();
    }

    #pragma unroll
    for (int nt = 0; nt < 4; ++nt) {
        int col = n0 + wn + nt * 16 + l16;
        float bias = bih[col] + bhh[col];
        #pragma unroll
        for (int mt = 0; mt < 4; ++mt) {
            #pragma unroll
            for (int r = 0; r < 4; ++r) {
                int row = m0 + wm + mt * 16 + quad * 4 + r;
                C[(size_t)row * GATES + col] = acc[mt][nt][r] + bias;
            }
        }
    }
}

// ---------------------------------------------------------------------------
// Persistent recurrent chunk: 64 blocks x 512 thr, TCHUNK steps, global
// barrier between steps. Block bk owns units j0=16*bk..+15 (64 gate rows,
// row for (type,u) = type*1024 + j0 + u). Weights in VGPRs (breg, loaded
// once). Waves: bh = batch-half, gh = gate-half, kh = K-half. K-partials
// reduced via LDS; activation fused; c in registers for the whole chunk.
// ---------------------------------------------------------------------------
__global__ __launch_bounds__(NTHR, 2) void lstm_chunk(
    const bf16*  __restrict__ whbf,   // [4096][1024]
    const float* __restrict__ xin,    // [TCHUNK][B][4096] (proj + biases)
    bf16* hA, bf16* hB,               // ping-pong h [B][1024]
    float* __restrict__ cbuf,         // [B][1024] (persisted across chunks)
    float* __restrict__ hf32,         // layer0: [B][1024], else null
    bf16*  __restrict__ seqbf,        // layer0: chunk slice of seq1bf, else null
    float* __restrict__ seqf,         // layer1: chunk slice of out, else null
    unsigned* bar, unsigned bar_base)
{
    __shared__ float partial[2][64][67];   // [kh][batch][gate-local], pad 67

    const int tid  = threadIdx.x;
    const int bk   = blockIdx.x;
    const int lane = tid & 63;
    const int wv   = tid >> 6;          // 0..7
    const int bh   = wv & 1;
    const int gh   = (wv >> 1) & 1;
    const int kh   = wv >> 2;
    const int quad = lane >> 4;
    const int l16  = lane & 15;
    const int j0   = bk * 16;

    // ---- weights -> registers (2 nt x 16 ksteps x 4 VGPR = 128 VGPRs) ----
    bf16x8 breg[2][16];
    #pragma unroll
    for (int nt = 0; nt < 2; ++nt) {
        int n   = gh * 32 + nt * 16 + l16;               // local gate row
        int grr = (n >> 4) * 1024 + j0 + (n & 15);       // global gate row
        const bf16* wp = whbf + (size_t)grr * HID + kh * 512 + quad * 8;
        #pragma unroll
        for (int ks = 0; ks < 16; ++ks)
            breg[nt][ks] = *(const bf16x8*)(wp + ks * 32);
    }

    // ---- c in registers: thread owns cells (cb, cu) and (cb, cu+1) ----
    const int cb = tid >> 3;            // batch 0..63
    const int cu = (tid & 7) * 2;       // unit 0,2,..,14
    float2 creg = *(const float2*)(cbuf + (size_t)cb * HID + j0 + cu);

    const int aoff0 = (bh * 32 + l16) * HID + kh * 512 + quad * 8;
    const int aoff1 = aoff0 + 16 * HID;

    for (int s = 0; s < TCHUNK; ++s) {
        const bf16* hin  = (s & 1) ? hB : hA;
        bf16*       hout = (s & 1) ? hA : hB;
        const float* xg  = xin + (size_t)s * BATCH * GATES;

        f32x4 acc[2][2] = {};
        #pragma unroll
        for (int ks = 0; ks < 16; ++ks) {
            bf16x8 a0 = *(const bf16x8*)(hin + aoff0 + ks * 32);
            bf16x8 a1 = *(const bf16x8*)(hin + aoff1 + ks * 32);
            acc[0][0] = __builtin_amdgcn_mfma_f32_16x16x32_bf16(a0, breg[0][ks], acc[0][0], 0, 0, 0);
            acc[0][1] = __builtin_amdgcn_mfma_f32_16x16x32_bf16(a0, breg[1][ks], acc[0][1], 0, 0, 0);
            acc[1][0] = __builtin_amdgcn_mfma_f32_16x16x32_bf16(a1, breg[0][ks], acc[1][0], 0, 0, 0);
            acc[1][1] = __builtin_amdgcn_mfma_f32_16x16x32_bf16(a1, breg[1][ks], acc[1][1], 0, 0, 0);
        }

        // partials -> LDS (D layout: row = quad*4+r, col = l16)
        #pragma unroll
        for (int mt = 0; mt < 2; ++mt)
            #pragma unroll
            for (int nt = 0; nt < 2; ++nt)
                #pragma unroll
                for (int r = 0; r < 4; ++r)
                    partial[kh][bh * 32 + mt * 16 + quad * 4 + r]
                           [gh * 32 + nt * 16 + l16] = acc[mt][nt][r];
        __syncthreads();

        // ---- fused reduce + activation: 2 cells per thread ----
        float2 xi = *(const float2*)(xg + (size_t)cb * GATES + 0 * HID + j0 + cu);
        float2 xf = *(const float2*)(xg + (size_t)cb * GATES + 1 * HID + j0 + cu);
        float2 xc = *(const float2*)(xg + (size_t)cb * GATES + 2 * HID + j0 + cu);
        float2 xo = *(const float2*)(xg + (size_t)cb * GATES + 3 * HID + j0 + cu);

        float hn2[2], cn2[2];
        #pragma unroll
        for (int e = 0; e < 2; ++e) {
            int u = cu + e;
            float gi = partial[0][cb][u]      + partial[1][cb][u]      + (e ? xi.y : xi.x);
            float gf = partial[0][cb][16 + u] + partial[1][cb][16 + u] + (e ? xf.y : xf.x);
            float gg = partial[0][cb][32 + u] + partial[1][cb][32 + u] + (e ? xc.y : xc.x);
            float go = partial[0][cb][48 + u] + partial[1][cb][48 + u] + (e ? xo.y : xo.x);
            float si = 1.f / (1.f + expf(-gi));
            float sf = 1.f / (1.f + expf(-gf));
            float so = 1.f / (1.f + expf(-go));
            float cv = (e ? creg.y : creg.x);
            float cn = sf * cv + si * tanhf(gg);
            float hn = so * tanhf(cn);
            cn2[e] = cn; hn2[e] = hn;
        }
        creg.x = cn2[0]; creg.y = cn2[1];

        bf16 hb[2] = {(bf16)hn2[0], (bf16)hn2[1]};
        size_t hidx = (size_t)cb * HID + j0 + cu;
        *(uint32_t*)(hout + hidx) = *(uint32_t*)hb;
        if (seqbf) *(uint32_t*)(seqbf + (size_t)s * BATCH * HID + hidx) = *(uint32_t*)hb;
        if (seqf)  { float2 v = {hn2[0], hn2[1]};
                     *(float2*)(seqf + (size_t)s * BATCH * HID + hidx) = v; }
        if (hf32)  { float2 v = {hn2[0], hn2[1]};
                     *(float2*)(hf32 + hidx) = v; }

        // ---- device-wide barrier (skip after last step) ----
        if (s != TCHUNK - 1) {
            __threadfence();            // release: drain + wb L2
            __syncthreads();
            if (tid == 0) {
                atomicAdd(bar, 1u);
                unsigned target = bar_base + (unsigned)(s + 1) * NBLK;
                while (__hip_atomic_load(bar, __ATOMIC_RELAXED,
                                         __HIP_MEMORY_SCOPE_AGENT) < target)
                    __builtin_amdgcn_s_sleep(1);
            }
            __syncthreads();
            __threadfence();            // acquire: invalidate stale L1/L2
        }
    }

    *(float2*)(cbuf + (size_t)cb * HID + j0 + cu) = creg;
}

// ---------------------------------------------------------------------------
extern "C" void kernel_launch(void* const* d_in, const int* in_sizes, int n_in,
                              void* d_out, int out_size, void* d_ws, size_t ws_size,
                              hipStream_t stream) {
    const float* x    = (const float*)d_in[0];
    const float* w_ih = (const float*)d_in[1];
    const float* w_hh = (const float*)d_in[2];
    const float* b_ih = (const float*)d_in[3];
    const float* b_hh = (const float*)d_in[4];
    float* out = (float*)d_out;

    // ws layout (~145 MB)
    float* xin  = (float*)d_ws;                               // 16,777,216 f
    float* cbuf = xin + (size_t)TCHUNK * BATCH * GATES;       // 65,536 f
    float* hf32 = cbuf + (size_t)BATCH * HID;                 // 65,536 f
    unsigned* bar = (unsigned*)(hf32 + (size_t)BATCH * HID);  // 64 u32
    bf16* seq1bf = (bf16*)(bar + 64);                         // 33,554,432 bf16
    bf16* wibf   = seq1bf + (size_t)T_LEN * BATCH * HID;      // 4M bf16
    bf16* whbf   = wibf + (size_t)GATES * IN_DIM;             // 4M bf16
    bf16* hA     = whbf + (size_t)GATES * HID;                // 65,536 bf16
    bf16* hB     = hA + (size_t)BATCH * HID;

    const size_t seqE = (size_t)T_LEN * BATCH * HID;
    const size_t BH   = (size_t)BATCH * HID;

    hipMemsetAsync(bar, 0, 64 * sizeof(unsigned), stream);

    for (int l = 0; l < NLAYERS; ++l) {
        const float* wi = w_ih + (size_t)l * GATES * IN_DIM;
        const float* wh = w_hh + (size_t)l * GATES * HID;
        const float* bi = b_ih + (size_t)l * GATES;
        const float* bh = b_hh + (size_t)l * GATES;

        cvt_bf16<<<(GATES * IN_DIM / 4 + 255) / 256, 256, 0, stream>>>(wi, wibf, GATES * IN_DIM / 4);
        cvt_bf16<<<(GATES * HID / 4 + 255) / 256, 256, 0, stream>>>(wh, whbf, GATES * HID / 4);

        hipMemsetAsync(hA, 0, BH * sizeof(bf16), stream);     // h(-1) = 0
        hipMemsetAsync(cbuf, 0, BH * sizeof(float), stream);  // c(-1) = 0

        for (int ch = 0; ch < T_LEN / TCHUNK; ++ch) {
            if (l == 0) {
                const float* Ab = x + (size_t)ch * TCHUNK * BATCH * IN_DIM;
                gemm_xin<true><<<dim3(GATES / 128, TCHUNK * BATCH / 128), 256, 0, stream>>>(
                    Ab, wibf, bi, bh, xin);
            } else {
                const bf16* Ab = seq1bf + (size_t)ch * TCHUNK * BATCH * HID;
                gemm_xin<false><<<dim3(GATES / 128, TCHUNK * BATCH / 128), 256, 0, stream>>>(
                    Ab, wibf, bi, bh, xin);
            }
            unsigned lo = (unsigned)(l * (T_LEN / TCHUNK) + ch);
            lstm_chunk<<<NBLK, NTHR, 0, stream>>>(
                whbf, xin, hA, hB, cbuf,
                (l == 0) ? hf32 : nullptr,
                (l == 0) ? (seq1bf + (size_t)ch * TCHUNK * BH) : nullptr,
                (l == 1) ? (out + (size_t)ch * TCHUNK * BH) : nullptr,
                bar, lo * (unsigned)((TCHUNK - 1) * NBLK));
        }

        if (l == 0) {
            hipMemcpyAsync(out + seqE, hf32, BH * sizeof(float),
                           hipMemcpyDeviceToDevice, stream);
        } else {
            hipMemcpyAsync(out + seqE + BH, out + (size_t)(T_LEN - 1) * BH,
                           BH * sizeof(float), hipMemcpyDeviceToDevice, stream);
        }
        hipMemcpyAsync(out + seqE + (size_t)(NLAYERS + l) * BH, cbuf,
                       BH * sizeof(float), hipMemcpyDeviceToDevice, stream);
    }
}